// Round 6
// baseline (365.624 us; speedup 1.0000x reference)
//
#include <hip/hip_runtime.h>
#include <math.h>

#define UNITS 100000
#define BATCH 512
#define DIM 512
#define BN 64
#define BM 256                         /* rows per block (half batch) */
#define NCT 1563                       /* column tiles */
#define SCALE 64.0f
#define COS_M2 0.87758256189037271612f /* cos(0.5) */
#define SIN_M2 0.47942553860420300027f /* sin(0.5) */
#define LOG2E  1.44269504088896340736f

typedef _Float16 half8 __attribute__((ext_vector_type(8)));
typedef float floatx4 __attribute__((ext_vector_type(4)));

// B-granule index (half units): granule = 8 k-contig halfs for (kg, col); low-3-bit
// col XOR by kg spreads the 4 rowg read-groups across banks.
#define BSWZ(kg, col) ((((kg) * 64) + ((col) ^ ((kg) & 7))) * 8)

// ---------------- Kernel 1: row-normalize inputs -> fragment-ordered fp16 A2 (x64) ----
__global__ void norm_emb_k(const float* __restrict__ inp, _Float16* __restrict__ A2) {
    const int row = blockIdx.x;
    const int lane = threadIdx.x;             // 64 threads = 1 wave
    const float* rp = inp + row * DIM + lane * 8;
    float v[8];
#pragma unroll
    for (int j = 0; j < 8; ++j) v[j] = rp[j];
    float ss = 0.f;
#pragma unroll
    for (int j = 0; j < 8; ++j) ss += v[j] * v[j];
#pragma unroll
    for (int off = 32; off > 0; off >>= 1) ss += __shfl_xor(ss, off);
    const float inv = SCALE / sqrtf(ss);      // fold s=64 into A
    half8 h;
#pragma unroll
    for (int j = 0; j < 8; ++j) h[j] = (_Float16)(v[j] * inv);
    const int idx = ((((row >> 4) * 16 + (lane >> 2)) * 64) + (row & 15) + 16 * (lane & 3)) * 8;
    *(half8*)(A2 + idx) = h;
}

// ---------------- Kernel 2: fused GEMM + col-norm + margin + tile-shifted exp ---------
// Block = 256 rows x 64 cols, K=512. All 16 w-loads (dwordx4) issued upfront; K staged
// as two 32KB LDS halves (3 barriers total); A-fragments depth-2 prefetched from L2.
template<bool HALF>
__global__ __launch_bounds__(512, 3) void gemmfused_k(
    const float* __restrict__ w, const _Float16* __restrict__ A2,
    const int* __restrict__ label,
    _Float16* __restrict__ vh, float* __restrict__ outf,
    float* __restrict__ psum, float* __restrict__ pmax) {
    __shared__ _Float16 Bt[16384];       // 32 KB: 256 k x 64 cols, swizzled granules
    __shared__ float sqred[8][64];
    __shared__ float cninv_s[64];
    __shared__ float sums_s[BM];
    __shared__ float maxs_s[BM];

    const int t = threadIdx.x;
    const int ctile = blockIdx.x >> 1;
    const int half = blockIdx.x & 1;
    const int c0 = ctile * BN;
    const int w8 = t >> 6;
    const int lane = t & 63;
    const int colg = lane & 15;
    const int rowg = lane >> 4;
    const int q = t & 15;                // col quad
    const int kr0 = t >> 4;              // 0..31

    const bool cval = (c0 + 4 * q) < UNITS;   // 32-col tail is quad-aligned
    const float* wp = w + (size_t)kr0 * UNITS + (cval ? (c0 + 4 * q) : 0);

    // ---- issue ALL 16 tile loads upfront (16B/lane, vmcnt-counted consume) ----
    floatx4 st[16];
#pragma unroll
    for (int i = 0; i < 16; ++i)
        st[i] = *(const floatx4*)(wp + (size_t)i * 32 * UNITS);

    float sq[4] = {0.f, 0.f, 0.f, 0.f};

    // ---- consume first 8 (k 0..255) -> LDS ----
#pragma unroll
    for (int i = 0; i < 8; ++i) {
        const int krl = i * 32 + kr0;
#pragma unroll
        for (int e = 0; e < 4; ++e) {
            const float x = cval ? st[i][e] : 0.f;
            sq[e] += x * x;
            Bt[BSWZ(krl >> 3, 4 * q + e) + (krl & 7)] = (_Float16)x;
        }
    }
    __syncthreads();

    floatx4 acc[2][4];
#pragma unroll
    for (int mf = 0; mf < 2; ++mf)
#pragma unroll
        for (int nf = 0; nf < 4; ++nf) acc[mf][nf] = (floatx4){0.f, 0.f, 0.f, 0.f};

    const _Float16* Aw = A2 + (size_t)(half * 16 + w8 * 2) * 8192 + lane * 8;

#pragma unroll
    for (int kc = 0; kc < 2; ++kc) {
        half8 ap[2][2];
#pragma unroll
        for (int mf = 0; mf < 2; ++mf) {
            ap[0][mf] = *(const half8*)(Aw + mf * 8192 + (kc * 8 + 0) * 512);
            ap[1][mf] = *(const half8*)(Aw + mf * 8192 + (kc * 8 + 1) * 512);
        }
#pragma unroll
        for (int ks = 0; ks < 8; ++ks) {
            half8 b[4];
#pragma unroll
            for (int nf = 0; nf < 4; ++nf)
                b[nf] = *(const half8*)&Bt[BSWZ(ks * 4 + rowg, nf * 16 + colg)];
            const half8 a0 = ap[ks & 1][0];
            const half8 a1 = ap[ks & 1][1];
            if (ks + 2 < 8) {            // depth-2 prefetch into freed slot
                ap[ks & 1][0] = *(const half8*)(Aw + 0 * 8192 + (kc * 8 + ks + 2) * 512);
                ap[ks & 1][1] = *(const half8*)(Aw + 1 * 8192 + (kc * 8 + ks + 2) * 512);
            }
#pragma unroll
            for (int nf = 0; nf < 4; ++nf) {
                acc[0][nf] = __builtin_amdgcn_mfma_f32_16x16x32_f16(a0, b[nf], acc[0][nf], 0, 0, 0);
                acc[1][nf] = __builtin_amdgcn_mfma_f32_16x16x32_f16(a1, b[nf], acc[1][nf], 0, 0, 0);
            }
        }
        if (kc == 0) {
            __syncthreads();             // half-1 reads done; restage from held regs
#pragma unroll
            for (int i = 8; i < 16; ++i) {
                const int krl = (i - 8) * 32 + kr0;
#pragma unroll
                for (int e = 0; e < 4; ++e) {
                    const float x = cval ? st[i][e] : 0.f;
                    sq[e] += x * x;
                    Bt[BSWZ(krl >> 3, 4 * q + e) + (krl & 7)] = (_Float16)x;
                }
            }
            __syncthreads();
        }
    }

    // ---- column inv-norms (f32) ----
#pragma unroll
    for (int e = 0; e < 4; ++e) {
        sq[e] += __shfl_xor(sq[e], 16);
        sq[e] += __shfl_xor(sq[e], 32);
    }
    if (lane < 16) {
#pragma unroll
        for (int e = 0; e < 4; ++e) sqred[w8][4 * lane + e] = sq[e];
    }
    __syncthreads();
    if (t < 64) {
        float s = 0.f;
#pragma unroll
        for (int g = 0; g < 8; ++g) s += sqred[g][t];
        cninv_s[t] = rsqrtf(s);
    }
    __syncthreads();

    float cn[4];
#pragma unroll
    for (int nf = 0; nf < 4; ++nf) cn[nf] = cninv_s[nf * 16 + colg];

    // ---- epilogue: margin, per-(row,tile) shifted exp, LDS bounce, coalesced vh ----
    _Float16* bounce = Bt + w8 * 2048;   // per-wave 16 rows x 64 cols fp16

#pragma unroll
    for (int mf = 0; mf < 2; ++mf) {
#pragma unroll
        for (int r = 0; r < 4; ++r) {
            const int Rl = w8 * 32 + mf * 16 + rowg * 4 + r;
            const int Rg = half * BM + Rl;
            const int labv = label[Rg];
            float lg[4];
            float mx = -1e30f;
#pragma unroll
            for (int nf = 0; nf < 4; ++nf) {
                const int C = c0 + nf * 16 + colg;
                float x = acc[mf][nf][r] * cn[nf];   // 64*cos(theta)
                if (C == labv) {
                    float cs = fminf(1.f, fmaxf(-1.f, x * (1.0f / SCALE)));
                    x = SCALE * (cs * COS_M2 - sqrtf(fmaxf(0.f, 1.f - cs * cs)) * SIN_M2);
                }
                if (C >= UNITS) x = -1e30f;
                lg[nf] = x;
                mx = fmaxf(mx, x);
            }
            mx = fmaxf(mx, __shfl_xor(mx, 1));
            mx = fmaxf(mx, __shfl_xor(mx, 2));
            mx = fmaxf(mx, __shfl_xor(mx, 4));
            mx = fmaxf(mx, __shfl_xor(mx, 8));
            float s = 0.f;
#pragma unroll
            for (int nf = 0; nf < 4; ++nf) {
                const int C = c0 + nf * 16 + colg;
                const float e = exp2f((lg[nf] - mx) * LOG2E);
                s += (C < UNITS) ? e : 0.f;
                if (HALF) bounce[(rowg * 4 + r) * 64 + nf * 16 + colg] = (_Float16)e;
                else if (C < UNITS) outf[(size_t)Rg * UNITS + C] = e;
            }
            s += __shfl_xor(s, 1);
            s += __shfl_xor(s, 2);
            s += __shfl_xor(s, 4);
            s += __shfl_xor(s, 8);
            if (colg == 0) { sums_s[Rl] = s; maxs_s[Rl] = mx; }
        }
        if (HALF) {
            // wave-local readback: 8 lanes x 16B contiguous per row (128B segments)
#pragma unroll
            for (int p = 0; p < 2; ++p) {
                const int row_l = p * 8 + (lane >> 3);
                const int seg = lane & 7;
                const int gc = c0 + seg * 8;
                const half8 hv = *(const half8*)&bounce[row_l * 64 + seg * 8];
                if (gc + 8 <= UNITS)
                    *(half8*)(vh + (size_t)(half * BM + w8 * 32 + mf * 16 + row_l) * UNITS + gc) = hv;
            }
        }
    }

    // ---- coalesced psum/pmax block stores ----
    __syncthreads();
    if (t < BM) {
        psum[(size_t)blockIdx.x * BM + t] = sums_s[t];
        pmax[(size_t)blockIdx.x * BM + t] = maxs_s[t];
    }
}

// ---------------- Kernel 3: per-row global max + sum -> per-(row,tile) factor ---------
__global__ void rowfac_k(const float* __restrict__ psum, const float* __restrict__ pmax,
                         float* __restrict__ fac) {
    const int row = blockIdx.x;
    const int lane = threadIdx.x;   // 64
    const int hb = row >> 8;
    const int rl = row & 255;
    float mx = -1e30f;
    for (int b = lane; b < NCT; b += 64)
        mx = fmaxf(mx, pmax[(size_t)(b * 2 + hb) * BM + rl]);
#pragma unroll
    for (int off = 32; off > 0; off >>= 1) mx = fmaxf(mx, __shfl_xor(mx, off));
    float s = 0.f;
    for (int b = lane; b < NCT; b += 64)
        s += psum[(size_t)(b * 2 + hb) * BM + rl] *
             exp2f((pmax[(size_t)(b * 2 + hb) * BM + rl] - mx) * LOG2E);
#pragma unroll
    for (int off = 32; off > 0; off >>= 1) s += __shfl_xor(s, off);
    const float invS = 1.0f / s;
    for (int b = lane; b < NCT; b += 64)
        fac[(size_t)row * NCT + b] =
            exp2f((pmax[(size_t)(b * 2 + hb) * BM + rl] - mx) * LOG2E) * invS;
}

// ---------------- Kernel 4: scale ----------------
__global__ void scale_half_k(const _Float16* __restrict__ v, const float* __restrict__ fac,
                             float* __restrict__ out) {
    const int row = blockIdx.y;
    const int c = (blockIdx.x * 256 + threadIdx.x) * 8;
    if (c >= UNITS) return;
    const float f = fac[(size_t)row * NCT + (c >> 6)];
    const half8 h = *(const half8*)(v + (size_t)row * UNITS + c);
    float4 o1, o2;
    o1.x = (float)h[0] * f; o1.y = (float)h[1] * f; o1.z = (float)h[2] * f; o1.w = (float)h[3] * f;
    o2.x = (float)h[4] * f; o2.y = (float)h[5] * f; o2.z = (float)h[6] * f; o2.w = (float)h[7] * f;
    float* op = out + (size_t)row * UNITS + c;
    *(float4*)op = o1;
    *(float4*)(op + 4) = o2;
}

__global__ void scale_f32_k(float* __restrict__ out, const float* __restrict__ fac) {
    const int row = blockIdx.y;
    const int c = (blockIdx.x * 256 + threadIdx.x) * 8;
    if (c >= UNITS) return;
    const float f = fac[(size_t)row * NCT + (c >> 6)];
    float* op = out + (size_t)row * UNITS + c;
    float4 o1 = *(float4*)op;
    float4 o2 = *(float4*)(op + 4);
    o1.x *= f; o1.y *= f; o1.z *= f; o1.w *= f;
    o2.x *= f; o2.y *= f; o2.z *= f; o2.w *= f;
    *(float4*)op = o1;
    *(float4*)(op + 4) = o2;
}

extern "C" void kernel_launch(void* const* d_in, const int* in_sizes, int n_in,
                              void* d_out, int out_size, void* d_ws, size_t ws_size,
                              hipStream_t stream) {
    const float* inp   = (const float*)d_in[0];
    const int*   label = (const int*)d_in[1];
    const float* w     = (const float*)d_in[2];
    float* out = (float*)d_out;

    char* ws = (char*)d_ws;
    _Float16* A2 = (_Float16*)ws;                 // 512 KB
    float* psum  = (float*)(ws + (4u << 20));     // 3.2 MB
    float* pmax  = (float*)(ws + (8u << 20));     // 3.2 MB
    float* fac   = (float*)(ws + (12u << 20));    // 3.2 MB
    _Float16* vh = (_Float16*)(ws + (16u << 20)); // 102.4 MB
    const size_t need = (size_t)(16u << 20) + (size_t)BATCH * UNITS * 2;
    const bool half_path = ws_size >= need;

    norm_emb_k<<<BATCH, 64, 0, stream>>>(inp, A2);
    if (half_path)
        gemmfused_k<true><<<NCT * 2, 512, 0, stream>>>(w, A2, label, vh, out, psum, pmax);
    else
        gemmfused_k<false><<<NCT * 2, 512, 0, stream>>>(w, A2, label, vh, out, psum, pmax);
    rowfac_k<<<BATCH, 64, 0, stream>>>(psum, pmax, fac);
    dim3 sg((UNITS + 2047) / 2048, BATCH);
    if (half_path)
        scale_half_k<<<sg, 256, 0, stream>>>(vh, fac, out);
    else
        scale_f32_k<<<sg, 256, 0, stream>>>(out, fac);
}